// Round 3
// baseline (169.003 us; speedup 1.0000x reference)
//
#include <hip/hip_runtime.h>
#include <math.h>

#define N_NODES 50000
#define N_EDGES 800000
#define DIM 128
#define DEG_CAP 48                            // max deg ~ Poisson(16); far tail ~1e-10/node
#define BINS ((N_NODES + 255) / 256)          // 196 dst-bins of 256 nodes
#define BIN_CAP 8192                          // mean 4082 edges/bin; +64 sd
#define EA_CHUNK 3125                         // edges per binA block
#define BA_BLOCKS ((N_EDGES + EA_CHUNK - 1) / EA_CHUNK)   // 256: chunk/bin ~16 edges = 64B line

#define LB_BLOCKS ((N_NODES + 255) / 256)     // 196 label-bucket blocks
#define WT_BLOCKS ((7 * DIM * DIM + 255) / 256) // 448 W-transpose blocks
#define K1_GRID (BA_BLOCKS + LB_BLOCKS + WT_BLOCKS) // 900

#define TR_BLOCKS 1568                        // 6272 waves >= 2*3133 tile-halves
#define K2_GRID (BINS + TR_BLOCKS)            // 1764

typedef __attribute__((ext_vector_type(8))) short short8;
typedef __attribute__((ext_vector_type(4))) float floatx4;

__device__ __forceinline__ unsigned short f2bf(float f) {
    unsigned int u = __float_as_uint(f);
    unsigned int r = (u + 0x7fff + ((u >> 16) & 1)) >> 16;  // RNE
    return (unsigned short)r;
}
__device__ __forceinline__ float bf2f_lo(unsigned int v) { return __uint_as_float(v << 16); }
__device__ __forceinline__ float bf2f_hi(unsigned int v) { return __uint_as_float(v & 0xffff0000u); }

// ---------------- Kernel 1: binA | label bucket | W^T (all input-only) ----------------
// binA: coarse-bin edges by dst>>8 with per-block LDS histogram + one global
// reservation per (block,bin). Chunk per (block,bin) ~64B -> dense line writes
// (R1 lesson: 2B random scatter = 48MB partial-sector writeback @ ~1TB/s = 50us).
__global__ __launch_bounds__(256) void build_kernel(
        const int* __restrict__ src, const int* __restrict__ dst,
        const int* __restrict__ label, const float* __restrict__ W,
        unsigned short* __restrict__ Wt,
        int* __restrict__ bin_cur, unsigned int* __restrict__ binned,
        int* __restrict__ lab_cnt, int* __restrict__ node_list) {
    int t = threadIdx.x;
    int blk = blockIdx.x;

    if (blk < BA_BLOCKS) {
        __shared__ int hist[BINS], base_s[BINS], rank[BINS];
        for (int i = t; i < BINS; i += 256) { hist[i] = 0; rank[i] = 0; }
        __syncthreads();
        int e0 = blk * EA_CHUNK;
        int e1 = e0 + EA_CHUNK; if (e1 > N_EDGES) e1 = N_EDGES;
        for (int e = e0 + t; e < e1; e += 256) atomicAdd(&hist[dst[e] >> 8], 1);
        __syncthreads();
        for (int i = t; i < BINS; i += 256)
            base_s[i] = (hist[i] > 0) ? atomicAdd(&bin_cur[i], hist[i]) : 0;
        __syncthreads();
        for (int e = e0 + t; e < e1; e += 256) {
            int d = dst[e];
            int b = d >> 8;
            int r = atomicAdd(&rank[b], 1);
            int slot = base_s[b] + r;
            if (slot < BIN_CAP)
                binned[(size_t)b * BIN_CAP + slot] = (unsigned int)(src[e] | ((d & 255) << 16));
        }
    } else if (blk < BA_BLOCKS + LB_BLOCKS) {
        // --- one-pass label bucketing into fixed per-label regions node_list[b*N ..] ---
        __shared__ int lcnt[8], lbase[8], lrank[8];
        int i = (blk - BA_BLOCKS) * 256 + t;
        if (t < 8) { lcnt[t] = 0; lrank[t] = 0; }
        __syncthreads();
        int b = -1;
        if (i < N_NODES) {
            int lab = label[i];
            b = (lab >= 1 && lab <= 7) ? (lab - 1) : 7;
            atomicAdd(&lcnt[b], 1);
        }
        __syncthreads();
        if (t < 8) lbase[t] = (lcnt[t] > 0) ? atomicAdd(&lab_cnt[t], lcnt[t]) : 0;
        __syncthreads();
        if (i < N_NODES) {
            int r = atomicAdd(&lrank[b], 1);
            node_list[(size_t)b * N_NODES + lbase[b] + r] = i;
        }
    } else {
        // --- W -> W^T bf16 ---
        int j = (blk - BA_BLOCKS - LB_BLOCKS) * 256 + t;
        if (j < 7 * DIM * DIM) {
            int b = j >> 14;
            int d = (j >> 7) & 127;
            int c = j & 127;
            Wt[((size_t)b * DIM + c) * DIM + d] = f2bf(W[j]);
        }
    }
}

// ---------------- Kernel 2: binB (counting sort into padded LDS rows) | MFMA transform ----------------
// Transform parallelism doubled (R2 lesson: 3136 waves = 3 waves/SIMD couldn't hide
// scattered-x / L2-Wt latency): each tile is handled by a wave PAIR in one block,
// half = output cols [half*64, half*64+64). pi/pj partials -> atomicAdd (ai/aj zeroed).
__global__ __launch_bounds__(256) void phase2_kernel(
        const float* __restrict__ x, const float* __restrict__ att,
        const int* __restrict__ lab_cnt, const int* __restrict__ node_list,
        const unsigned short* __restrict__ Wt,
        const int* __restrict__ bin_cur, const unsigned int* __restrict__ binned,
        unsigned short* __restrict__ oxh, float* __restrict__ ai, float* __restrict__ aj,
        int* __restrict__ cnt, unsigned short* __restrict__ bucket) {
    int t = threadIdx.x;
    int blk = blockIdx.x;

    if (blk < BINS) {
        // --- binB: sort one 256-node bin into padded LDS rows, bulk-write 24KB coalesced ---
        __shared__ unsigned short rows[256][DEG_CAP];   // 24 KB
        __shared__ int lcnt[256];
        int b = blk;
        int m = bin_cur[b]; if (m > BIN_CAP) m = BIN_CAP;
        const unsigned int* bp = binned + (size_t)b * BIN_CAP;

        lcnt[t] = 0;
        __syncthreads();
        for (int i = t; i < m; i += 256) {
            unsigned int v = bp[i];
            int ln = (v >> 16) & 255;
            int p = atomicAdd(&lcnt[ln], 1);
            if (p < DEG_CAP) rows[ln][p] = (unsigned short)(v & 0xFFFF);
        }
        __syncthreads();
        int n = b * 256 + t;
        if (n < N_NODES) {
            int deg = lcnt[t];
            if (deg > DEG_CAP) deg = DEG_CAP;
            cnt[n] = deg;
        }
        // bulk coalesced write of the bin's whole bucket region (bucket padded to BINS*256 rows)
        uint4* gdst = (uint4*)(bucket + (size_t)b * 256 * DEG_CAP);
        const uint4* lsrc = (const uint4*)rows;
        #pragma unroll
        for (int k = 0; k < (256 * DEG_CAP * 2 / 16) / 256; k++)   // 6 iters
            gdst[t + k * 256] = lsrc[t + k * 256];
    } else {
        // --- MFMA transform: wave-pair per 16-node tile; A-frags f2bf'd in-register ---
        int wv = t >> 6;
        int lane = t & 63;
        int gw = (blk - BINS) * 4 + wv;
        int tile = gw >> 1;
        int half = gw & 1;

        int b = 0, base = 0, tcnt = 0;
        for (; b < 8; b++) {
            int c = lab_cnt[b];
            int nt = (c + 15) >> 4;
            if (tile < nt) { base = b * N_NODES + tile * 16; tcnt = c - tile * 16; break; }
            tile -= nt;
        }
        if (b == 8) return;
        if (tcnt > 16) tcnt = 16;

        int m = lane & 15;
        int quad = lane >> 4;

        floatx4 acc[4];
        #pragma unroll
        for (int nt = 0; nt < 4; nt++) acc[nt] = (floatx4){0.f, 0.f, 0.f, 0.f};

        if (b < 7) {
            int mm = (m < tcnt) ? m : 0;
            int nodeA = node_list[base + mm];
            const float* xrow = x + (size_t)nodeA * DIM;
            short8 afrag[4];
            #pragma unroll
            for (int kk = 0; kk < 4; kk++) {
                float4 f0 = *(const float4*)(xrow + kk * 32 + quad * 8);
                float4 f1 = *(const float4*)(xrow + kk * 32 + quad * 8 + 4);
                short8 a;
                a[0] = (short)f2bf(f0.x); a[1] = (short)f2bf(f0.y);
                a[2] = (short)f2bf(f0.z); a[3] = (short)f2bf(f0.w);
                a[4] = (short)f2bf(f1.x); a[5] = (short)f2bf(f1.y);
                a[6] = (short)f2bf(f1.z); a[7] = (short)f2bf(f1.w);
                afrag[kk] = a;
            }

            const unsigned short* WtB = Wt + (size_t)b * DIM * DIM;
            #pragma unroll
            for (int kk = 0; kk < 4; kk++) {
                #pragma unroll
                for (int nt = 0; nt < 4; nt++) {
                    short8 bfrag = *(const short8*)(WtB + (size_t)(half * 64 + nt * 16 + m) * DIM + kk * 32 + quad * 8);
                    acc[nt] = __builtin_amdgcn_mfma_f32_16x16x32_bf16(afrag[kk], bfrag, acc[nt], 0, 0, 0);
                }
            }
        }

        int nodes[4];
        #pragma unroll
        for (int r = 0; r < 4; r++) {
            int rw = quad * 4 + r;
            nodes[r] = node_list[base + ((rw < tcnt) ? rw : 0)];
        }
        float pi[4] = {0.f, 0.f, 0.f, 0.f};
        float pj[4] = {0.f, 0.f, 0.f, 0.f};
        #pragma unroll
        for (int nt = 0; nt < 4; nt++) {
            int c = half * 64 + nt * 16 + m;
            float a1 = att[c];
            float a2 = att[DIM + c];
            #pragma unroll
            for (int r = 0; r < 4; r++) {
                int rw = quad * 4 + r;
                if (rw < tcnt) {
                    float xv = x[(size_t)nodes[r] * DIM + c];
                    float v = (b < 7) ? (acc[nt][r] + xv) : xv;
                    oxh[(size_t)nodes[r] * DIM + c] = f2bf(v);
                    pi[r] += v * a1;
                    pj[r] += v * a2;
                }
            }
        }
        #pragma unroll
        for (int r = 0; r < 4; r++) {
            #pragma unroll
            for (int off = 1; off < 16; off <<= 1) {
                pi[r] += __shfl_xor(pi[r], off, 64);
                pj[r] += __shfl_xor(pj[r], off, 64);
            }
            int rw = quad * 4 + r;
            if (m == 0 && rw < tcnt) {
                atomicAdd(&ai[nodes[r]], pi[r]);
                atomicAdd(&aj[nodes[r]], pj[r]);
            }
        }
    }
}

// ---------------- Gather: wave per node; 4x16-lane groups, dwordx4 loads ----------------
// Phase A (lane-per-edge): softmax weights wn -> LDS arrays (R2 lesson: per-iteration
// __shfl chain serialized one memory op per wave; LDS scalars + unroll-2 doubles MLP).
// Grid covers 50000 = 12500*4 exactly -> no early wave exit -> __syncthreads safe.
__global__ __launch_bounds__(256) void gather7_kernel(
        const int* __restrict__ cnt, const unsigned short* __restrict__ bucket,
        const float* __restrict__ ai, const float* __restrict__ aj,
        const uint4* __restrict__ tab,     // oxh rows as 16 x uint4
        float* __restrict__ out) {
    __shared__ float wls[4][64];
    __shared__ int   sls[4][64];
    int wv = threadIdx.x >> 6;
    int lane = threadIdx.x & 63;
    int n = blockIdx.x * 4 + wv;
    int deg = cnt[n];
    if (deg > DEG_CAP) deg = DEG_CAP;
    const unsigned short* row = bucket + (size_t)n * DEG_CAP;
    float ain = ai[n];

    // phase A: lane i<deg = edge i; lane==deg = self loop; others weight 0
    float a = -INFINITY;
    int s = n;
    if (lane < deg) {
        s = row[lane];
        a = ain + aj[s];
        a = (a > 0.0f) ? a : 0.2f * a;
    } else if (lane == deg) {
        a = ain + aj[n];
        a = (a > 0.0f) ? a : 0.2f * a;
    }
    float mx = a;
    #pragma unroll
    for (int off = 32; off > 0; off >>= 1) mx = fmaxf(mx, __shfl_xor(mx, off, 64));
    float w = expf(a - mx);
    float ssum = w;
    #pragma unroll
    for (int off = 32; off > 0; off >>= 1) ssum += __shfl_xor(ssum, off, 64);
    float wn = w / (ssum + 1e-16f);

    wls[wv][lane] = wn;          // lanes > deg hold 0; lane == deg holds self weight
    sls[wv][lane] = s;
    __syncthreads();

    const float* wp = wls[wv];
    const int*   sp = sls[wv];
    float wsf = wp[deg];         // self-loop weight

    // phase B
    int g = lane >> 4;      // edge group 0..3
    int cl = lane & 15;     // col-block: cols [cl*8, cl*8+8)
    float ac0 = 0.f, ac1 = 0.f, ac2 = 0.f, ac3 = 0.f;
    float ac4 = 0.f, ac5 = 0.f, ac6 = 0.f, ac7 = 0.f;

    if (g == 0) {           // self row, counted once
        uint4 v = tab[(size_t)n * 16 + cl];
        ac0 += wsf * bf2f_lo(v.x); ac1 += wsf * bf2f_hi(v.x);
        ac2 += wsf * bf2f_lo(v.y); ac3 += wsf * bf2f_hi(v.y);
        ac4 += wsf * bf2f_lo(v.z); ac5 += wsf * bf2f_hi(v.z);
        ac6 += wsf * bf2f_lo(v.w); ac7 += wsf * bf2f_hi(v.w);
    }

    int niter = (deg + 3) >> 2;          // wave-uniform trip count; i max 47 < 64
    int k = 0;
    for (; k + 2 <= niter; k += 2) {     // unroll 2: two rows in flight
        int i0 = g + 4 * k;
        int i1 = i0 + 4;
        float w0 = wp[i0]; int s0 = sp[i0];
        float w1 = wp[i1]; int s1 = sp[i1];
        if (i0 >= deg) w0 = 0.0f;        // lane==deg slot is the SELF weight: mask it
        if (i1 >= deg) w1 = 0.0f;
        uint4 v0 = tab[(size_t)s0 * 16 + cl];
        uint4 v1 = tab[(size_t)s1 * 16 + cl];
        ac0 += w0 * bf2f_lo(v0.x); ac1 += w0 * bf2f_hi(v0.x);
        ac2 += w0 * bf2f_lo(v0.y); ac3 += w0 * bf2f_hi(v0.y);
        ac4 += w0 * bf2f_lo(v0.z); ac5 += w0 * bf2f_hi(v0.z);
        ac6 += w0 * bf2f_lo(v0.w); ac7 += w0 * bf2f_hi(v0.w);
        ac0 += w1 * bf2f_lo(v1.x); ac1 += w1 * bf2f_hi(v1.x);
        ac2 += w1 * bf2f_lo(v1.y); ac3 += w1 * bf2f_hi(v1.y);
        ac4 += w1 * bf2f_lo(v1.z); ac5 += w1 * bf2f_hi(v1.z);
        ac6 += w1 * bf2f_lo(v1.w); ac7 += w1 * bf2f_hi(v1.w);
    }
    if (k < niter) {
        int i0 = g + 4 * k;
        float w0 = (i0 < deg) ? wp[i0] : 0.0f;
        int s0 = sp[i0];
        uint4 v0 = tab[(size_t)s0 * 16 + cl];
        ac0 += w0 * bf2f_lo(v0.x); ac1 += w0 * bf2f_hi(v0.x);
        ac2 += w0 * bf2f_lo(v0.y); ac3 += w0 * bf2f_hi(v0.y);
        ac4 += w0 * bf2f_lo(v0.z); ac5 += w0 * bf2f_hi(v0.z);
        ac6 += w0 * bf2f_lo(v0.w); ac7 += w0 * bf2f_hi(v0.w);
    }

    // cross-group reduction (groups hold same cols at lane offsets 16/32/48)
    #pragma unroll
    for (int off = 16; off < 64; off <<= 1) {
        ac0 += __shfl_xor(ac0, off, 64); ac1 += __shfl_xor(ac1, off, 64);
        ac2 += __shfl_xor(ac2, off, 64); ac3 += __shfl_xor(ac3, off, 64);
        ac4 += __shfl_xor(ac4, off, 64); ac5 += __shfl_xor(ac5, off, 64);
        ac6 += __shfl_xor(ac6, off, 64); ac7 += __shfl_xor(ac7, off, 64);
    }
    if (g == 0) {
        float* op = out + (size_t)n * DIM + cl * 8;
        float4 o0; o0.x = ac0; o0.y = ac1; o0.z = ac2; o0.w = ac3;
        float4 o1; o1.x = ac4; o1.y = ac5; o1.z = ac6; o1.w = ac7;
        *(float4*)op = o0;
        *(float4*)(op + 4) = o1;
    }
}

extern "C" void kernel_launch(void* const* d_in, const int* in_sizes, int n_in,
                              void* d_out, int out_size, void* d_ws, size_t ws_size,
                              hipStream_t stream) {
    const float* x     = (const float*)d_in[0];
    const int*   ei    = (const int*)d_in[1];   // [2, E]
    const int*   label = (const int*)d_in[2];
    const float* W     = (const float*)d_in[3]; // [7, D, D]
    const float* att   = (const float*)d_in[4]; // [1, 1, 2D]
    float* out = (float*)d_out;

    const int* src = ei;
    const int* dst = ei + N_EDGES;

    // workspace (~27 MB). bucket padded to BINS*256 rows for binB's bulk write.
    char* w = (char*)d_ws;
    unsigned short* oxh    = (unsigned short*)w; w += sizeof(unsigned short) * (size_t)N_NODES * DIM;
    unsigned short* Wt     = (unsigned short*)w; w += sizeof(unsigned short) * 7 * DIM * DIM;
    unsigned short* bucket = (unsigned short*)w; w += sizeof(unsigned short) * (size_t)BINS * 256 * DEG_CAP;
    unsigned int*   binned = (unsigned int*)w;   w += sizeof(unsigned int) * (size_t)BINS * BIN_CAP;
    int*   cnt       = (int*)w;    w += sizeof(int) * N_NODES;
    int*   node_list = (int*)w;    w += sizeof(int) * (size_t)8 * N_NODES;
    // zero-region: ai + aj + lab_cnt + bin_cur contiguous, one memset
    float* ai        = (float*)w;  w += sizeof(float) * N_NODES;
    float* aj        = (float*)w;  w += sizeof(float) * N_NODES;
    int*   lab_cnt   = (int*)w;    w += sizeof(int) * 8;
    int*   bin_cur   = (int*)w;    w += sizeof(int) * BINS;

    hipMemsetAsync(ai, 0, sizeof(float) * 2 * N_NODES + sizeof(int) * (8 + BINS), stream);

    build_kernel<<<K1_GRID, 256, 0, stream>>>(src, dst, label, W,
                                              Wt, bin_cur, binned, lab_cnt, node_list);

    phase2_kernel<<<K2_GRID, 256, 0, stream>>>(x, att, lab_cnt, node_list, Wt,
                                               bin_cur, binned, oxh, ai, aj, cnt, bucket);

    gather7_kernel<<<(N_NODES + 3) / 4, 256, 0, stream>>>(cnt, bucket, ai, aj,
                                                          (const uint4*)oxh, out);
}

// Round 4
// 156.507 us; speedup vs baseline: 1.0798x; 1.0798x over previous
//
#include <hip/hip_runtime.h>
#include <math.h>

#define N_NODES 50000
#define N_EDGES 800000
#define DIM 128
#define DEG_CAP 48                            // max deg ~ Poisson(16); far tail ~1e-10/node
#define BINS ((N_NODES + 255) / 256)          // 196 dst-bins of 256 nodes
#define BIN_CAP 8192                          // mean 4082 edges/bin; +64 sd
#define EA_CHUNK 3125                         // edges per binA block
#define BA_BLOCKS ((N_EDGES + EA_CHUNK - 1) / EA_CHUNK)   // 256: chunk/bin ~16 edges = 64B line

#define LB_BLOCKS ((N_NODES + 255) / 256)     // 196 label-bucket blocks
#define WT_BLOCKS ((7 * DIM * DIM + 255) / 256) // 448 W-transpose blocks
#define K1_GRID (BA_BLOCKS + LB_BLOCKS + WT_BLOCKS) // 900

#define TR_TILES 3133                         // max Σ_b ceil(c_b/16) over 8 buckets
#define K2_GRID (BINS + TR_TILES)             // 3329

#define XS_STRIDE 132                         // 128 + 4 pad: 2-way LDS bank alias (free)

typedef __attribute__((ext_vector_type(8))) short short8;
typedef __attribute__((ext_vector_type(4))) float floatx4;

__device__ __forceinline__ unsigned short f2bf(float f) {
    unsigned int u = __float_as_uint(f);
    unsigned int r = (u + 0x7fff + ((u >> 16) & 1)) >> 16;  // RNE
    return (unsigned short)r;
}
__device__ __forceinline__ float bf2f_lo(unsigned int v) { return __uint_as_float(v << 16); }
__device__ __forceinline__ float bf2f_hi(unsigned int v) { return __uint_as_float(v & 0xffff0000u); }

// ---------------- Kernel 1: binA | label bucket | W^T (all input-only) ----------------
// binA: coarse-bin edges by dst>>8 with per-block LDS histogram + one global
// reservation per (block,bin). Chunk per (block,bin) ~64B -> dense line writes
// (R1 lesson: 2B random scatter = 48MB partial-sector writeback @ ~1TB/s = 50us).
__global__ __launch_bounds__(256) void build_kernel(
        const int* __restrict__ src, const int* __restrict__ dst,
        const int* __restrict__ label, const float* __restrict__ W,
        unsigned short* __restrict__ Wt,
        int* __restrict__ bin_cur, unsigned int* __restrict__ binned,
        int* __restrict__ lab_cnt, int* __restrict__ node_list) {
    int t = threadIdx.x;
    int blk = blockIdx.x;

    if (blk < BA_BLOCKS) {
        __shared__ int hist[BINS], base_s[BINS], rank[BINS];
        for (int i = t; i < BINS; i += 256) { hist[i] = 0; rank[i] = 0; }
        __syncthreads();
        int e0 = blk * EA_CHUNK;
        int e1 = e0 + EA_CHUNK; if (e1 > N_EDGES) e1 = N_EDGES;
        for (int e = e0 + t; e < e1; e += 256) atomicAdd(&hist[dst[e] >> 8], 1);
        __syncthreads();
        for (int i = t; i < BINS; i += 256)
            base_s[i] = (hist[i] > 0) ? atomicAdd(&bin_cur[i], hist[i]) : 0;
        __syncthreads();
        for (int e = e0 + t; e < e1; e += 256) {
            int d = dst[e];
            int b = d >> 8;
            int r = atomicAdd(&rank[b], 1);
            int slot = base_s[b] + r;
            if (slot < BIN_CAP)
                binned[(size_t)b * BIN_CAP + slot] = (unsigned int)(src[e] | ((d & 255) << 16));
        }
    } else if (blk < BA_BLOCKS + LB_BLOCKS) {
        // --- one-pass label bucketing into fixed per-label regions node_list[b*N ..] ---
        __shared__ int lcnt[8], lbase[8], lrank[8];
        int i = (blk - BA_BLOCKS) * 256 + t;
        if (t < 8) { lcnt[t] = 0; lrank[t] = 0; }
        __syncthreads();
        int b = -1;
        if (i < N_NODES) {
            int lab = label[i];
            b = (lab >= 1 && lab <= 7) ? (lab - 1) : 7;
            atomicAdd(&lcnt[b], 1);
        }
        __syncthreads();
        if (t < 8) lbase[t] = (lcnt[t] > 0) ? atomicAdd(&lab_cnt[t], lcnt[t]) : 0;
        __syncthreads();
        if (i < N_NODES) {
            int r = atomicAdd(&lrank[b], 1);
            node_list[(size_t)b * N_NODES + lbase[b] + r] = i;
        }
    } else {
        // --- W -> W^T bf16 ---
        int j = (blk - BA_BLOCKS - LB_BLOCKS) * 256 + t;
        if (j < 7 * DIM * DIM) {
            int b = j >> 14;
            int d = (j >> 7) & 127;
            int c = j & 127;
            Wt[((size_t)b * DIM + c) * DIM + d] = f2bf(W[j]);
        }
    }
}

// ---------------- Kernel 2: binB (counting sort) | LDS-staged MFMA transform ----------------
// Transform (R3 lesson: col-split waves duplicated the full-K A-fragment reads):
// one BLOCK per 16-node tile; x rows staged once, coalesced, into LDS (fp32, stride
// 132 = 2-way bank alias, free). 4 waves each own a 32-col quarter: A-frags f2bf'd
// from LDS, residual + pi/pj from LDS fp32 (numerics unchanged), ai/aj cross-wave
// reduced via LDS -> plain stores (no atomics, no zero-init).
__global__ __launch_bounds__(256) void phase2_kernel(
        const float* __restrict__ x, const float* __restrict__ att,
        const int* __restrict__ lab_cnt, const int* __restrict__ node_list,
        const unsigned short* __restrict__ Wt,
        const int* __restrict__ bin_cur, const unsigned int* __restrict__ binned,
        unsigned short* __restrict__ oxh, float* __restrict__ ai, float* __restrict__ aj,
        int* __restrict__ cnt, unsigned short* __restrict__ bucket) {
    __shared__ __align__(16) char smem[25600];   // union: binB 25600B | transform 8960B
    int t = threadIdx.x;
    int blk = blockIdx.x;

    if (blk < BINS) {
        // --- binB: sort one 256-node bin into padded LDS rows, bulk-write 24KB coalesced ---
        unsigned short (*rows)[DEG_CAP] = (unsigned short (*)[DEG_CAP])smem;  // 24576 B
        int* lcnt = (int*)(smem + 24576);                                     // 1024 B
        int b = blk;
        int m = bin_cur[b]; if (m > BIN_CAP) m = BIN_CAP;
        const unsigned int* bp = binned + (size_t)b * BIN_CAP;

        lcnt[t] = 0;
        __syncthreads();
        for (int i = t; i < m; i += 256) {
            unsigned int v = bp[i];
            int ln = (v >> 16) & 255;
            int p = atomicAdd(&lcnt[ln], 1);
            if (p < DEG_CAP) rows[ln][p] = (unsigned short)(v & 0xFFFF);
        }
        __syncthreads();
        int n = b * 256 + t;
        if (n < N_NODES) {
            int deg = lcnt[t];
            if (deg > DEG_CAP) deg = DEG_CAP;
            cnt[n] = deg;
        }
        // bulk coalesced write of the bin's whole bucket region (bucket padded to BINS*256 rows)
        uint4* gdst = (uint4*)(bucket + (size_t)b * 256 * DEG_CAP);
        const uint4* lsrc = (const uint4*)rows;
        #pragma unroll
        for (int k = 0; k < (256 * DEG_CAP * 2 / 16) / 256; k++)   // 6 iters
            gdst[t + k * 256] = lsrc[t + k * 256];
    } else {
        // --- MFMA transform: block per tile, wave per 32-col quarter ---
        int tile = blk - BINS;
        int b = 0, base = 0, tcnt = 0;
        for (; b < 8; b++) {
            int c = lab_cnt[b];
            int nt = (c + 15) >> 4;
            if (tile < nt) { base = b * N_NODES + tile * 16; tcnt = c - tile * 16; break; }
            tile -= nt;
        }
        if (b == 8) return;            // block-uniform: safe before barriers
        if (tcnt > 16) tcnt = 16;

        float* xs  = (float*)smem;                 // [16][XS_STRIDE] = 8448 B
        float* red = (float*)(smem + 16 * XS_STRIDE * 4);  // [4][32] = 512 B

        // stage 16 x-rows coalesced (512B each): 512 float4 over 256 threads
        {
            const float4* x4 = (const float4*)x;
            int j = t;
            #pragma unroll
            for (int k = 0; k < 2; k++, j += 256) {
                int row = j >> 5;          // 0..15
                int c4  = j & 31;
                int node = node_list[base + ((row < tcnt) ? row : 0)];
                float4 v = x4[(size_t)node * 32 + c4];
                *(float4*)(xs + row * XS_STRIDE + c4 * 4) = v;
            }
        }
        __syncthreads();

        int wv = t >> 6;
        int lane = t & 63;
        int m = lane & 15;
        int quad = lane >> 4;

        floatx4 acc[2];
        acc[0] = (floatx4){0.f, 0.f, 0.f, 0.f};
        acc[1] = (floatx4){0.f, 0.f, 0.f, 0.f};

        if (b < 7) {
            short8 afrag[4];
            #pragma unroll
            for (int kk = 0; kk < 4; kk++) {
                const float* xp = xs + m * XS_STRIDE + kk * 32 + quad * 8;
                short8 a;
                #pragma unroll
                for (int e = 0; e < 8; e++) a[e] = (short)f2bf(xp[e]);
                afrag[kk] = a;
            }
            const unsigned short* WtB = Wt + (size_t)b * DIM * DIM;
            #pragma unroll
            for (int kk = 0; kk < 4; kk++) {
                #pragma unroll
                for (int nl = 0; nl < 2; nl++) {
                    int c = wv * 32 + nl * 16 + m;
                    short8 bfrag = *(const short8*)(WtB + (size_t)c * DIM + kk * 32 + quad * 8);
                    acc[nl] = __builtin_amdgcn_mfma_f32_16x16x32_bf16(afrag[kk], bfrag, acc[nl], 0, 0, 0);
                }
            }
        }

        int nodes[4];
        #pragma unroll
        for (int r = 0; r < 4; r++) {
            int rw = quad * 4 + r;
            nodes[r] = node_list[base + ((rw < tcnt) ? rw : 0)];
        }
        float pi[4] = {0.f, 0.f, 0.f, 0.f};
        float pj[4] = {0.f, 0.f, 0.f, 0.f};
        #pragma unroll
        for (int nl = 0; nl < 2; nl++) {
            int c = wv * 32 + nl * 16 + m;
            float a1 = att[c];
            float a2 = att[DIM + c];
            #pragma unroll
            for (int r = 0; r < 4; r++) {
                int rw = quad * 4 + r;
                if (rw < tcnt) {
                    float xv = xs[rw * XS_STRIDE + c];       // fp32 residual from LDS
                    float v = (b < 7) ? (acc[nl][r] + xv) : xv;
                    oxh[(size_t)nodes[r] * DIM + c] = f2bf(v);
                    pi[r] += v * a1;
                    pj[r] += v * a2;
                }
            }
        }
        #pragma unroll
        for (int r = 0; r < 4; r++) {
            #pragma unroll
            for (int off = 1; off < 16; off <<= 1) {
                pi[r] += __shfl_xor(pi[r], off, 64);
                pj[r] += __shfl_xor(pj[r], off, 64);
            }
        }
        if (m == 0) {
            #pragma unroll
            for (int r = 0; r < 4; r++) {
                red[wv * 32 + quad * 4 + r]      = pi[r];
                red[wv * 32 + 16 + quad * 4 + r] = pj[r];
            }
        }
        __syncthreads();
        if (t < 16 && t < tcnt) {
            int node = node_list[base + t];
            float si = 0.f, sj = 0.f;
            #pragma unroll
            for (int w2 = 0; w2 < 4; w2++) {
                si += red[w2 * 32 + t];
                sj += red[w2 * 32 + 16 + t];
            }
            ai[node] = si;
            aj[node] = sj;
        }
    }
}

// ---------------- Gather: wave per node; 4x16-lane groups, dwordx4 loads ----------------
// Phase A (lane-per-edge): softmax weights wn -> LDS arrays. Phase B: wave-uniform
// niter = ceil(deg/4) <= 12, unroll-4 -> 4 independent row loads in flight (R3
// lesson: unroll-2 + shfl removal wasn't enough MLP).
// Grid covers 50000 = 12500*4 exactly -> no early wave exit -> __syncthreads safe.
__global__ __launch_bounds__(256) void gather8_kernel(
        const int* __restrict__ cnt, const unsigned short* __restrict__ bucket,
        const float* __restrict__ ai, const float* __restrict__ aj,
        const uint4* __restrict__ tab,     // oxh rows as 16 x uint4
        float* __restrict__ out) {
    __shared__ float wls[4][64];
    __shared__ int   sls[4][64];
    int wv = threadIdx.x >> 6;
    int lane = threadIdx.x & 63;
    int n = blockIdx.x * 4 + wv;
    int deg = cnt[n];
    if (deg > DEG_CAP) deg = DEG_CAP;
    const unsigned short* row = bucket + (size_t)n * DEG_CAP;
    float ain = ai[n];

    // phase A: lane i<deg = edge i; lane==deg = self loop; others weight 0
    float a = -INFINITY;
    int s = n;
    if (lane < deg) {
        s = row[lane];
        a = ain + aj[s];
        a = (a > 0.0f) ? a : 0.2f * a;
    } else if (lane == deg) {
        a = ain + aj[n];
        a = (a > 0.0f) ? a : 0.2f * a;
    }
    float mx = a;
    #pragma unroll
    for (int off = 32; off > 0; off >>= 1) mx = fmaxf(mx, __shfl_xor(mx, off, 64));
    float w = expf(a - mx);
    float ssum = w;
    #pragma unroll
    for (int off = 32; off > 0; off >>= 1) ssum += __shfl_xor(ssum, off, 64);
    float wn = w / (ssum + 1e-16f);

    wls[wv][lane] = wn;          // lanes > deg hold 0; lane == deg holds self weight
    sls[wv][lane] = s;
    __syncthreads();

    const float* wp = wls[wv];
    const int*   sp = sls[wv];
    float wsf = wp[deg];         // self-loop weight

    // phase B
    int g = lane >> 4;      // edge group 0..3
    int cl = lane & 15;     // col-block: cols [cl*8, cl*8+8)
    float ac0 = 0.f, ac1 = 0.f, ac2 = 0.f, ac3 = 0.f;
    float ac4 = 0.f, ac5 = 0.f, ac6 = 0.f, ac7 = 0.f;

    if (g == 0) {           // self row, counted once
        uint4 v = tab[(size_t)n * 16 + cl];
        ac0 += wsf * bf2f_lo(v.x); ac1 += wsf * bf2f_hi(v.x);
        ac2 += wsf * bf2f_lo(v.y); ac3 += wsf * bf2f_hi(v.y);
        ac4 += wsf * bf2f_lo(v.z); ac5 += wsf * bf2f_hi(v.z);
        ac6 += wsf * bf2f_lo(v.w); ac7 += wsf * bf2f_hi(v.w);
    }

    int niter = (deg + 3) >> 2;          // wave-uniform; max 12 (i max 47 < 64)
    int k = 0;
    for (; k + 4 <= niter; k += 4) {     // unroll 4: four rows in flight
        int i0 = g + 4 * k, i1 = i0 + 4, i2 = i0 + 8, i3 = i0 + 12;
        float w0 = wp[i0]; int s0 = sp[i0];
        float w1 = wp[i1]; int s1 = sp[i1];
        float w2 = wp[i2]; int s2 = sp[i2];
        float w3 = wp[i3]; int s3 = sp[i3];
        if (i0 >= deg) w0 = 0.0f;        // lane==deg slot is the SELF weight: mask it
        if (i1 >= deg) w1 = 0.0f;
        if (i2 >= deg) w2 = 0.0f;
        if (i3 >= deg) w3 = 0.0f;
        uint4 v0 = tab[(size_t)s0 * 16 + cl];
        uint4 v1 = tab[(size_t)s1 * 16 + cl];
        uint4 v2 = tab[(size_t)s2 * 16 + cl];
        uint4 v3 = tab[(size_t)s3 * 16 + cl];
        ac0 += w0 * bf2f_lo(v0.x); ac1 += w0 * bf2f_hi(v0.x);
        ac2 += w0 * bf2f_lo(v0.y); ac3 += w0 * bf2f_hi(v0.y);
        ac4 += w0 * bf2f_lo(v0.z); ac5 += w0 * bf2f_hi(v0.z);
        ac6 += w0 * bf2f_lo(v0.w); ac7 += w0 * bf2f_hi(v0.w);
        ac0 += w1 * bf2f_lo(v1.x); ac1 += w1 * bf2f_hi(v1.x);
        ac2 += w1 * bf2f_lo(v1.y); ac3 += w1 * bf2f_hi(v1.y);
        ac4 += w1 * bf2f_lo(v1.z); ac5 += w1 * bf2f_hi(v1.z);
        ac6 += w1 * bf2f_lo(v1.w); ac7 += w1 * bf2f_hi(v1.w);
        ac0 += w2 * bf2f_lo(v2.x); ac1 += w2 * bf2f_hi(v2.x);
        ac2 += w2 * bf2f_lo(v2.y); ac3 += w2 * bf2f_hi(v2.y);
        ac4 += w2 * bf2f_lo(v2.z); ac5 += w2 * bf2f_hi(v2.z);
        ac6 += w2 * bf2f_lo(v2.w); ac7 += w2 * bf2f_hi(v2.w);
        ac0 += w3 * bf2f_lo(v3.x); ac1 += w3 * bf2f_hi(v3.x);
        ac2 += w3 * bf2f_lo(v3.y); ac3 += w3 * bf2f_hi(v3.y);
        ac4 += w3 * bf2f_lo(v3.z); ac5 += w3 * bf2f_hi(v3.z);
        ac6 += w3 * bf2f_lo(v3.w); ac7 += w3 * bf2f_hi(v3.w);
    }
    for (; k < niter; k++) {
        int i0 = g + 4 * k;
        float w0 = (i0 < deg) ? wp[i0] : 0.0f;
        int s0 = sp[i0];
        uint4 v0 = tab[(size_t)s0 * 16 + cl];
        ac0 += w0 * bf2f_lo(v0.x); ac1 += w0 * bf2f_hi(v0.x);
        ac2 += w0 * bf2f_lo(v0.y); ac3 += w0 * bf2f_hi(v0.y);
        ac4 += w0 * bf2f_lo(v0.z); ac5 += w0 * bf2f_hi(v0.z);
        ac6 += w0 * bf2f_lo(v0.w); ac7 += w0 * bf2f_hi(v0.w);
    }

    // cross-group reduction (groups hold same cols at lane offsets 16/32/48)
    #pragma unroll
    for (int off = 16; off < 64; off <<= 1) {
        ac0 += __shfl_xor(ac0, off, 64); ac1 += __shfl_xor(ac1, off, 64);
        ac2 += __shfl_xor(ac2, off, 64); ac3 += __shfl_xor(ac3, off, 64);
        ac4 += __shfl_xor(ac4, off, 64); ac5 += __shfl_xor(ac5, off, 64);
        ac6 += __shfl_xor(ac6, off, 64); ac7 += __shfl_xor(ac7, off, 64);
    }
    if (g == 0) {
        float* op = out + (size_t)n * DIM + cl * 8;
        float4 o0; o0.x = ac0; o0.y = ac1; o0.z = ac2; o0.w = ac3;
        float4 o1; o1.x = ac4; o1.y = ac5; o1.z = ac6; o1.w = ac7;
        *(float4*)op = o0;
        *(float4*)(op + 4) = o1;
    }
}

extern "C" void kernel_launch(void* const* d_in, const int* in_sizes, int n_in,
                              void* d_out, int out_size, void* d_ws, size_t ws_size,
                              hipStream_t stream) {
    const float* x     = (const float*)d_in[0];
    const int*   ei    = (const int*)d_in[1];   // [2, E]
    const int*   label = (const int*)d_in[2];
    const float* W     = (const float*)d_in[3]; // [7, D, D]
    const float* att   = (const float*)d_in[4]; // [1, 1, 2D]
    float* out = (float*)d_out;

    const int* src = ei;
    const int* dst = ei + N_EDGES;

    // workspace (~27 MB). bucket padded to BINS*256 rows for binB's bulk write.
    char* w = (char*)d_ws;
    unsigned short* oxh    = (unsigned short*)w; w += sizeof(unsigned short) * (size_t)N_NODES * DIM;
    unsigned short* Wt     = (unsigned short*)w; w += sizeof(unsigned short) * 7 * DIM * DIM;
    unsigned short* bucket = (unsigned short*)w; w += sizeof(unsigned short) * (size_t)BINS * 256 * DEG_CAP;
    unsigned int*   binned = (unsigned int*)w;   w += sizeof(unsigned int) * (size_t)BINS * BIN_CAP;
    int*   cnt       = (int*)w;    w += sizeof(int) * N_NODES;
    int*   node_list = (int*)w;    w += sizeof(int) * (size_t)8 * N_NODES;
    float* ai        = (float*)w;  w += sizeof(float) * N_NODES;
    float* aj        = (float*)w;  w += sizeof(float) * N_NODES;
    // zero-region: lab_cnt(8) + bin_cur(BINS) contiguous, one tiny memset (816 B)
    int*   lab_cnt   = (int*)w;    w += sizeof(int) * 8;
    int*   bin_cur   = (int*)w;    w += sizeof(int) * BINS;

    hipMemsetAsync(lab_cnt, 0, sizeof(int) * (8 + BINS), stream);

    build_kernel<<<K1_GRID, 256, 0, stream>>>(src, dst, label, W,
                                              Wt, bin_cur, binned, lab_cnt, node_list);

    phase2_kernel<<<K2_GRID, 256, 0, stream>>>(x, att, lab_cnt, node_list, Wt,
                                               bin_cur, binned, oxh, ai, aj, cnt, bucket);

    gather8_kernel<<<(N_NODES + 3) / 4, 256, 0, stream>>>(cnt, bucket, ai, aj,
                                                          (const uint4*)oxh, out);
}

// Round 5
// 151.038 us; speedup vs baseline: 1.1189x; 1.0362x over previous
//
#include <hip/hip_runtime.h>
#include <math.h>

#define N_NODES 50000
#define N_EDGES 800000
#define DIM 128
#define DEG_CAP 48                            // max deg ~ Poisson(16); far tail ~1e-10/node
#define BINS ((N_NODES + 255) / 256)          // 196 dst-bins of 256 nodes
#define BIN_CAP 8192                          // mean 4082 edges/bin; +64 sd
#define EA_CHUNK 3125                         // edges per binA block
#define BA_BLOCKS ((N_EDGES + EA_CHUNK - 1) / EA_CHUNK)   // 256: chunk/bin ~16 edges = 64B line
#define EA_UNR 13                             // ceil(3125/256) register-cached loads

#define LB_BLOCKS ((N_NODES + 255) / 256)     // 196 label-bucket blocks
#define WT_BLOCKS ((7 * DIM * DIM + 255) / 256) // 448 W-transpose blocks
#define K1_GRID (BA_BLOCKS + LB_BLOCKS + WT_BLOCKS) // 900

#define TR_TILES 3133                         // max Σ_b ceil(c_b/16) over 8 buckets
#define K2_GRID (BINS + TR_TILES)             // 3329

#define XS_STRIDE 132                         // 128 + 4 pad: 2-way LDS bank alias (free)

typedef __attribute__((ext_vector_type(8))) short short8;
typedef __attribute__((ext_vector_type(4))) float floatx4;

__device__ __forceinline__ unsigned short f2bf(float f) {
    unsigned int u = __float_as_uint(f);
    unsigned int r = (u + 0x7fff + ((u >> 16) & 1)) >> 16;  // RNE
    return (unsigned short)r;
}
__device__ __forceinline__ float bf2f_lo(unsigned int v) { return __uint_as_float(v << 16); }
__device__ __forceinline__ float bf2f_hi(unsigned int v) { return __uint_as_float(v & 0xffff0000u); }

// ---------------- Kernel 1: binA | label bucket | W^T (all input-only) ----------------
// binA: coarse-bin edges by dst>>8; LDS histogram + one global reservation per
// (block,bin); ~64B chunk per (block,bin) -> dense line writes (R1 lesson).
// R5: dst chunk register-cached via predicated unroll-13 (all loads in flight,
// pass 2 reuses registers -> one fewer 3.2MB pass + no serial load chains).
__global__ __launch_bounds__(256) void build_kernel(
        const int* __restrict__ src, const int* __restrict__ dst,
        const int* __restrict__ label, const float* __restrict__ W,
        unsigned short* __restrict__ Wt,
        int* __restrict__ bin_cur, unsigned int* __restrict__ binned,
        int* __restrict__ lab_cnt, int* __restrict__ node_list) {
    int t = threadIdx.x;
    int blk = blockIdx.x;

    if (blk < BA_BLOCKS) {
        __shared__ int hist[BINS], base_s[BINS], rank[BINS];
        for (int i = t; i < BINS; i += 256) { hist[i] = 0; rank[i] = 0; }
        __syncthreads();
        int e0 = blk * EA_CHUNK;
        int e1 = e0 + EA_CHUNK; if (e1 > N_EDGES) e1 = N_EDGES;
        int dl[EA_UNR];
        #pragma unroll
        for (int k = 0; k < EA_UNR; k++) {
            int e = e0 + t + k * 256;
            dl[k] = (e < e1) ? dst[e] : -1;     // all 13 loads independent, in flight
        }
        #pragma unroll
        for (int k = 0; k < EA_UNR; k++)
            if (dl[k] >= 0) atomicAdd(&hist[dl[k] >> 8], 1);
        __syncthreads();
        for (int i = t; i < BINS; i += 256)
            base_s[i] = (hist[i] > 0) ? atomicAdd(&bin_cur[i], hist[i]) : 0;
        __syncthreads();
        int sl[EA_UNR];
        #pragma unroll
        for (int k = 0; k < EA_UNR; k++) {
            int e = e0 + t + k * 256;
            sl[k] = (e < e1) ? src[e] : 0;
        }
        #pragma unroll
        for (int k = 0; k < EA_UNR; k++) {
            if (dl[k] >= 0) {
                int d = dl[k];
                int b = d >> 8;
                int r = atomicAdd(&rank[b], 1);
                int slot = base_s[b] + r;
                if (slot < BIN_CAP)
                    binned[(size_t)b * BIN_CAP + slot] = (unsigned int)(sl[k] | ((d & 255) << 16));
            }
        }
    } else if (blk < BA_BLOCKS + LB_BLOCKS) {
        // --- one-pass label bucketing into fixed per-label regions node_list[b*N ..] ---
        __shared__ int lcnt[8], lbase[8], lrank[8];
        int i = (blk - BA_BLOCKS) * 256 + t;
        if (t < 8) { lcnt[t] = 0; lrank[t] = 0; }
        __syncthreads();
        int b = -1;
        if (i < N_NODES) {
            int lab = label[i];
            b = (lab >= 1 && lab <= 7) ? (lab - 1) : 7;
            atomicAdd(&lcnt[b], 1);
        }
        __syncthreads();
        if (t < 8) lbase[t] = (lcnt[t] > 0) ? atomicAdd(&lab_cnt[t], lcnt[t]) : 0;
        __syncthreads();
        if (i < N_NODES) {
            int r = atomicAdd(&lrank[b], 1);
            node_list[(size_t)b * N_NODES + lbase[b] + r] = i;
        }
    } else {
        // --- W -> W^T bf16 ---
        int j = (blk - BA_BLOCKS - LB_BLOCKS) * 256 + t;
        if (j < 7 * DIM * DIM) {
            int b = j >> 14;
            int d = (j >> 7) & 127;
            int c = j & 127;
            Wt[((size_t)b * DIM + c) * DIM + d] = f2bf(W[j]);
        }
    }
}

// ---------------- Kernel 2: binB (counting sort) | LDS-staged MFMA transform ----------------
// binB R5: scan loop 4-deep unrolled -> 4 independent binned loads in flight
// (was 16 sequential load->atomic->store round trips at 1 block/CU).
__global__ __launch_bounds__(256) void phase2_kernel(
        const float* __restrict__ x, const float* __restrict__ att,
        const int* __restrict__ lab_cnt, const int* __restrict__ node_list,
        const unsigned short* __restrict__ Wt,
        const int* __restrict__ bin_cur, const unsigned int* __restrict__ binned,
        unsigned short* __restrict__ oxh, float* __restrict__ ai, float* __restrict__ aj,
        int* __restrict__ cnt, unsigned short* __restrict__ bucket) {
    __shared__ __align__(16) char smem[25600];   // union: binB 25600B | transform 8960B
    int t = threadIdx.x;
    int blk = blockIdx.x;

    if (blk < BINS) {
        // --- binB: sort one 256-node bin into padded LDS rows, bulk-write 24KB coalesced ---
        unsigned short (*rows)[DEG_CAP] = (unsigned short (*)[DEG_CAP])smem;  // 24576 B
        int* lcnt = (int*)(smem + 24576);                                     // 1024 B
        int b = blk;
        int m = bin_cur[b]; if (m > BIN_CAP) m = BIN_CAP;
        const unsigned int* bp = binned + (size_t)b * BIN_CAP;

        lcnt[t] = 0;
        __syncthreads();
        for (int i0 = 0; i0 < m; i0 += 1024) {
            unsigned int v[4];
            #pragma unroll
            for (int u = 0; u < 4; u++) {
                int i = i0 + u * 256 + t;
                v[u] = (i < m) ? bp[i] : 0u;    // 4 loads in flight
            }
            #pragma unroll
            for (int u = 0; u < 4; u++) {
                int i = i0 + u * 256 + t;
                if (i < m) {
                    int ln = (v[u] >> 16) & 255;
                    int p = atomicAdd(&lcnt[ln], 1);
                    if (p < DEG_CAP) rows[ln][p] = (unsigned short)(v[u] & 0xFFFF);
                }
            }
        }
        __syncthreads();
        int n = b * 256 + t;
        if (n < N_NODES) {
            int deg = lcnt[t];
            if (deg > DEG_CAP) deg = DEG_CAP;
            cnt[n] = deg;
        }
        // bulk coalesced write of the bin's whole bucket region (bucket padded to BINS*256 rows)
        uint4* gdst = (uint4*)(bucket + (size_t)b * 256 * DEG_CAP);
        const uint4* lsrc = (const uint4*)rows;
        #pragma unroll
        for (int k = 0; k < (256 * DEG_CAP * 2 / 16) / 256; k++)   // 6 iters
            gdst[t + k * 256] = lsrc[t + k * 256];
    } else {
        // --- MFMA transform: block per tile, wave per 32-col quarter ---
        int tile = blk - BINS;
        int b = 0, base = 0, tcnt = 0;
        for (; b < 8; b++) {
            int c = lab_cnt[b];
            int nt = (c + 15) >> 4;
            if (tile < nt) { base = b * N_NODES + tile * 16; tcnt = c - tile * 16; break; }
            tile -= nt;
        }
        if (b == 8) return;            // block-uniform: safe before barriers
        if (tcnt > 16) tcnt = 16;

        float* xs  = (float*)smem;                 // [16][XS_STRIDE] = 8448 B
        float* red = (float*)(smem + 16 * XS_STRIDE * 4);  // [4][32] = 512 B

        // stage 16 x-rows coalesced (512B each): 512 float4 over 256 threads
        {
            const float4* x4 = (const float4*)x;
            int j = t;
            #pragma unroll
            for (int k = 0; k < 2; k++, j += 256) {
                int row = j >> 5;          // 0..15
                int c4  = j & 31;
                int node = node_list[base + ((row < tcnt) ? row : 0)];
                float4 v = x4[(size_t)node * 32 + c4];
                *(float4*)(xs + row * XS_STRIDE + c4 * 4) = v;
            }
        }
        __syncthreads();

        int wv = t >> 6;
        int lane = t & 63;
        int m = lane & 15;
        int quad = lane >> 4;

        floatx4 acc[2];
        acc[0] = (floatx4){0.f, 0.f, 0.f, 0.f};
        acc[1] = (floatx4){0.f, 0.f, 0.f, 0.f};

        if (b < 7) {
            short8 afrag[4];
            #pragma unroll
            for (int kk = 0; kk < 4; kk++) {
                const float* xp = xs + m * XS_STRIDE + kk * 32 + quad * 8;
                short8 a;
                #pragma unroll
                for (int e = 0; e < 8; e++) a[e] = (short)f2bf(xp[e]);
                afrag[kk] = a;
            }
            const unsigned short* WtB = Wt + (size_t)b * DIM * DIM;
            #pragma unroll
            for (int kk = 0; kk < 4; kk++) {
                #pragma unroll
                for (int nl = 0; nl < 2; nl++) {
                    int c = wv * 32 + nl * 16 + m;
                    short8 bfrag = *(const short8*)(WtB + (size_t)c * DIM + kk * 32 + quad * 8);
                    acc[nl] = __builtin_amdgcn_mfma_f32_16x16x32_bf16(afrag[kk], bfrag, acc[nl], 0, 0, 0);
                }
            }
        }

        int nodes[4];
        #pragma unroll
        for (int r = 0; r < 4; r++) {
            int rw = quad * 4 + r;
            nodes[r] = node_list[base + ((rw < tcnt) ? rw : 0)];
        }
        float pi[4] = {0.f, 0.f, 0.f, 0.f};
        float pj[4] = {0.f, 0.f, 0.f, 0.f};
        #pragma unroll
        for (int nl = 0; nl < 2; nl++) {
            int c = wv * 32 + nl * 16 + m;
            float a1 = att[c];
            float a2 = att[DIM + c];
            #pragma unroll
            for (int r = 0; r < 4; r++) {
                int rw = quad * 4 + r;
                if (rw < tcnt) {
                    float xv = xs[rw * XS_STRIDE + c];       // fp32 residual from LDS
                    float v = (b < 7) ? (acc[nl][r] + xv) : xv;
                    oxh[(size_t)nodes[r] * DIM + c] = f2bf(v);
                    pi[r] += v * a1;
                    pj[r] += v * a2;
                }
            }
        }
        #pragma unroll
        for (int r = 0; r < 4; r++) {
            #pragma unroll
            for (int off = 1; off < 16; off <<= 1) {
                pi[r] += __shfl_xor(pi[r], off, 64);
                pj[r] += __shfl_xor(pj[r], off, 64);
            }
        }
        if (m == 0) {
            #pragma unroll
            for (int r = 0; r < 4; r++) {
                red[wv * 32 + quad * 4 + r]      = pi[r];
                red[wv * 32 + 16 + quad * 4 + r] = pj[r];
            }
        }
        __syncthreads();
        if (t < 16 && t < tcnt) {
            int node = node_list[base + t];
            float si = 0.f, sj = 0.f;
            #pragma unroll
            for (int w2 = 0; w2 < 4; w2++) {
                si += red[w2 * 32 + t];
                sj += red[w2 * 32 + 16 + t];
            }
            ai[node] = si;
            aj[node] = sj;
        }
    }
}

// ---------------- Gather: wave per node; 4x16-lane groups, dwordx4 loads ----------------
// Phase A (lane-per-edge): softmax weights wn -> LDS arrays. Phase B: wave-uniform
// niter = ceil(deg/4) <= 12, unroll-4 -> 4 independent row loads in flight.
// Grid covers 50000 = 12500*4 exactly -> no early wave exit -> __syncthreads safe.
__global__ __launch_bounds__(256) void gather8_kernel(
        const int* __restrict__ cnt, const unsigned short* __restrict__ bucket,
        const float* __restrict__ ai, const float* __restrict__ aj,
        const uint4* __restrict__ tab,     // oxh rows as 16 x uint4
        float* __restrict__ out) {
    __shared__ float wls[4][64];
    __shared__ int   sls[4][64];
    int wv = threadIdx.x >> 6;
    int lane = threadIdx.x & 63;
    int n = blockIdx.x * 4 + wv;
    int deg = cnt[n];
    if (deg > DEG_CAP) deg = DEG_CAP;
    const unsigned short* row = bucket + (size_t)n * DEG_CAP;
    float ain = ai[n];

    // phase A: lane i<deg = edge i; lane==deg = self loop; others weight 0
    float a = -INFINITY;
    int s = n;
    if (lane < deg) {
        s = row[lane];
        a = ain + aj[s];
        a = (a > 0.0f) ? a : 0.2f * a;
    } else if (lane == deg) {
        a = ain + aj[n];
        a = (a > 0.0f) ? a : 0.2f * a;
    }
    float mx = a;
    #pragma unroll
    for (int off = 32; off > 0; off >>= 1) mx = fmaxf(mx, __shfl_xor(mx, off, 64));
    float w = expf(a - mx);
    float ssum = w;
    #pragma unroll
    for (int off = 32; off > 0; off >>= 1) ssum += __shfl_xor(ssum, off, 64);
    float wn = w / (ssum + 1e-16f);

    wls[wv][lane] = wn;          // lanes > deg hold 0; lane == deg holds self weight
    sls[wv][lane] = s;
    __syncthreads();

    const float* wp = wls[wv];
    const int*   sp = sls[wv];
    float wsf = wp[deg];         // self-loop weight

    // phase B
    int g = lane >> 4;      // edge group 0..3
    int cl = lane & 15;     // col-block: cols [cl*8, cl*8+8)
    float ac0 = 0.f, ac1 = 0.f, ac2 = 0.f, ac3 = 0.f;
    float ac4 = 0.f, ac5 = 0.f, ac6 = 0.f, ac7 = 0.f;

    if (g == 0) {           // self row, counted once
        uint4 v = tab[(size_t)n * 16 + cl];
        ac0 += wsf * bf2f_lo(v.x); ac1 += wsf * bf2f_hi(v.x);
        ac2 += wsf * bf2f_lo(v.y); ac3 += wsf * bf2f_hi(v.y);
        ac4 += wsf * bf2f_lo(v.z); ac5 += wsf * bf2f_hi(v.z);
        ac6 += wsf * bf2f_lo(v.w); ac7 += wsf * bf2f_hi(v.w);
    }

    int niter = (deg + 3) >> 2;          // wave-uniform; max 12 (i max 47 < 64)
    int k = 0;
    for (; k + 4 <= niter; k += 4) {     // unroll 4: four rows in flight
        int i0 = g + 4 * k, i1 = i0 + 4, i2 = i0 + 8, i3 = i0 + 12;
        float w0 = wp[i0]; int s0 = sp[i0];
        float w1 = wp[i1]; int s1 = sp[i1];
        float w2 = wp[i2]; int s2 = sp[i2];
        float w3 = wp[i3]; int s3 = sp[i3];
        if (i0 >= deg) w0 = 0.0f;        // lane==deg slot is the SELF weight: mask it
        if (i1 >= deg) w1 = 0.0f;
        if (i2 >= deg) w2 = 0.0f;
        if (i3 >= deg) w3 = 0.0f;
        uint4 v0 = tab[(size_t)s0 * 16 + cl];
        uint4 v1 = tab[(size_t)s1 * 16 + cl];
        uint4 v2 = tab[(size_t)s2 * 16 + cl];
        uint4 v3 = tab[(size_t)s3 * 16 + cl];
        ac0 += w0 * bf2f_lo(v0.x); ac1 += w0 * bf2f_hi(v0.x);
        ac2 += w0 * bf2f_lo(v0.y); ac3 += w0 * bf2f_hi(v0.y);
        ac4 += w0 * bf2f_lo(v0.z); ac5 += w0 * bf2f_hi(v0.z);
        ac6 += w0 * bf2f_lo(v0.w); ac7 += w0 * bf2f_hi(v0.w);
        ac0 += w1 * bf2f_lo(v1.x); ac1 += w1 * bf2f_hi(v1.x);
        ac2 += w1 * bf2f_lo(v1.y); ac3 += w1 * bf2f_hi(v1.y);
        ac4 += w1 * bf2f_lo(v1.z); ac5 += w1 * bf2f_hi(v1.z);
        ac6 += w1 * bf2f_lo(v1.w); ac7 += w1 * bf2f_hi(v1.w);
        ac0 += w2 * bf2f_lo(v2.x); ac1 += w2 * bf2f_hi(v2.x);
        ac2 += w2 * bf2f_lo(v2.y); ac3 += w2 * bf2f_hi(v2.y);
        ac4 += w2 * bf2f_lo(v2.z); ac5 += w2 * bf2f_hi(v2.z);
        ac6 += w2 * bf2f_lo(v2.w); ac7 += w2 * bf2f_hi(v2.w);
        ac0 += w3 * bf2f_lo(v3.x); ac1 += w3 * bf2f_hi(v3.x);
        ac2 += w3 * bf2f_lo(v3.y); ac3 += w3 * bf2f_hi(v3.y);
        ac4 += w3 * bf2f_lo(v3.z); ac5 += w3 * bf2f_hi(v3.z);
        ac6 += w3 * bf2f_lo(v3.w); ac7 += w3 * bf2f_hi(v3.w);
    }
    for (; k < niter; k++) {
        int i0 = g + 4 * k;
        float w0 = (i0 < deg) ? wp[i0] : 0.0f;
        int s0 = sp[i0];
        uint4 v0 = tab[(size_t)s0 * 16 + cl];
        ac0 += w0 * bf2f_lo(v0.x); ac1 += w0 * bf2f_hi(v0.x);
        ac2 += w0 * bf2f_lo(v0.y); ac3 += w0 * bf2f_hi(v0.y);
        ac4 += w0 * bf2f_lo(v0.z); ac5 += w0 * bf2f_hi(v0.z);
        ac6 += w0 * bf2f_lo(v0.w); ac7 += w0 * bf2f_hi(v0.w);
    }

    // cross-group reduction (groups hold same cols at lane offsets 16/32/48)
    #pragma unroll
    for (int off = 16; off < 64; off <<= 1) {
        ac0 += __shfl_xor(ac0, off, 64); ac1 += __shfl_xor(ac1, off, 64);
        ac2 += __shfl_xor(ac2, off, 64); ac3 += __shfl_xor(ac3, off, 64);
        ac4 += __shfl_xor(ac4, off, 64); ac5 += __shfl_xor(ac5, off, 64);
        ac6 += __shfl_xor(ac6, off, 64); ac7 += __shfl_xor(ac7, off, 64);
    }
    if (g == 0) {
        float* op = out + (size_t)n * DIM + cl * 8;
        float4 o0; o0.x = ac0; o0.y = ac1; o0.z = ac2; o0.w = ac3;
        float4 o1; o1.x = ac4; o1.y = ac5; o1.z = ac6; o1.w = ac7;
        *(float4*)op = o0;
        *(float4*)(op + 4) = o1;
    }
}

extern "C" void kernel_launch(void* const* d_in, const int* in_sizes, int n_in,
                              void* d_out, int out_size, void* d_ws, size_t ws_size,
                              hipStream_t stream) {
    const float* x     = (const float*)d_in[0];
    const int*   ei    = (const int*)d_in[1];   // [2, E]
    const int*   label = (const int*)d_in[2];
    const float* W     = (const float*)d_in[3]; // [7, D, D]
    const float* att   = (const float*)d_in[4]; // [1, 1, 2D]
    float* out = (float*)d_out;

    const int* src = ei;
    const int* dst = ei + N_EDGES;

    // workspace (~27 MB). bucket padded to BINS*256 rows for binB's bulk write.
    char* w = (char*)d_ws;
    unsigned short* oxh    = (unsigned short*)w; w += sizeof(unsigned short) * (size_t)N_NODES * DIM;
    unsigned short* Wt     = (unsigned short*)w; w += sizeof(unsigned short) * 7 * DIM * DIM;
    unsigned short* bucket = (unsigned short*)w; w += sizeof(unsigned short) * (size_t)BINS * 256 * DEG_CAP;
    unsigned int*   binned = (unsigned int*)w;   w += sizeof(unsigned int) * (size_t)BINS * BIN_CAP;
    int*   cnt       = (int*)w;    w += sizeof(int) * N_NODES;
    int*   node_list = (int*)w;    w += sizeof(int) * (size_t)8 * N_NODES;
    float* ai        = (float*)w;  w += sizeof(float) * N_NODES;
    float* aj        = (float*)w;  w += sizeof(float) * N_NODES;
    // zero-region: lab_cnt(8) + bin_cur(BINS) contiguous, one tiny memset (816 B)
    int*   lab_cnt   = (int*)w;    w += sizeof(int) * 8;
    int*   bin_cur   = (int*)w;    w += sizeof(int) * BINS;

    hipMemsetAsync(lab_cnt, 0, sizeof(int) * (8 + BINS), stream);

    build_kernel<<<K1_GRID, 256, 0, stream>>>(src, dst, label, W,
                                              Wt, bin_cur, binned, lab_cnt, node_list);

    phase2_kernel<<<K2_GRID, 256, 0, stream>>>(x, att, lab_cnt, node_list, Wt,
                                               bin_cur, binned, oxh, ai, aj, cnt, bucket);

    gather8_kernel<<<(N_NODES + 3) / 4, 256, 0, stream>>>(cnt, bucket, ai, aj,
                                                          (const uint4*)oxh, out);
}

// Round 6
// 146.889 us; speedup vs baseline: 1.1505x; 1.0282x over previous
//
#include <hip/hip_runtime.h>
#include <math.h>

#define N_NODES 50000
#define N_EDGES 800000
#define DIM 128
#define DEG_CAP 48                            // max deg ~ Poisson(16); far tail ~1e-10/node
#define BINS ((N_NODES + 255) / 256)          // 196 dst-bins of 256 nodes
#define BIN_CAP 8192                          // mean 4082 edges/bin; +64 sd
#define EA_CHUNK 3125                         // edges per binA block
#define BA_BLOCKS ((N_EDGES + EA_CHUNK - 1) / EA_CHUNK)   // 256: chunk/bin ~16 edges = 64B line
#define EA_UNR 13                             // ceil(3125/256) register-cached loads

#define LB_BLOCKS ((N_NODES + 255) / 256)     // 196 label-bucket blocks
#define WT_BLOCKS ((7 * DIM * DIM + 255) / 256) // 448 W-transpose blocks
#define K1_GRID (BA_BLOCKS + LB_BLOCKS + WT_BLOCKS) // 900

#define TR_TILES 1571                         // >= max Σ_b ceil(c_b/32) (50000/32 + 8)
#define K2_GRID (BINS + TR_TILES)             // 1767

#define XS_STRIDE 132                         // 128 + 4 pad: float4-aligned, 2-way bank alias (free)

typedef __attribute__((ext_vector_type(8))) short short8;
typedef __attribute__((ext_vector_type(4))) float floatx4;

__device__ __forceinline__ unsigned short f2bf(float f) {
    unsigned int u = __float_as_uint(f);
    unsigned int r = (u + 0x7fff + ((u >> 16) & 1)) >> 16;  // RNE
    return (unsigned short)r;
}
// HW packed f32->bf16 (RNE): S0 -> bits[15:0], S1 -> bits[31:16]
__device__ __forceinline__ unsigned int cvtpk_bf16(float lo, float hi) {
    unsigned int r;
    asm volatile("v_cvt_pk_bf16_f32 %0, %1, %2" : "=v"(r) : "v"(lo), "v"(hi));
    return r;
}
__device__ __forceinline__ float bf2f_lo(unsigned int v) { return __uint_as_float(v << 16); }
__device__ __forceinline__ float bf2f_hi(unsigned int v) { return __uint_as_float(v & 0xffff0000u); }

// ---------------- Kernel 1: binA | label bucket | W^T (all input-only) ----------------
// binA: coarse-bin edges by dst>>8; LDS histogram + one global reservation per
// (block,bin); ~64B chunk per (block,bin) -> dense line writes (R1 lesson).
// dst chunk register-cached via predicated unroll-13 (R5: all loads in flight).
__global__ __launch_bounds__(256) void build_kernel(
        const int* __restrict__ src, const int* __restrict__ dst,
        const int* __restrict__ label, const float* __restrict__ W,
        unsigned short* __restrict__ Wt,
        int* __restrict__ bin_cur, unsigned int* __restrict__ binned,
        int* __restrict__ lab_cnt, int* __restrict__ node_list) {
    int t = threadIdx.x;
    int blk = blockIdx.x;

    if (blk < BA_BLOCKS) {
        __shared__ int hist[BINS], base_s[BINS], rank[BINS];
        for (int i = t; i < BINS; i += 256) { hist[i] = 0; rank[i] = 0; }
        __syncthreads();
        int e0 = blk * EA_CHUNK;
        int e1 = e0 + EA_CHUNK; if (e1 > N_EDGES) e1 = N_EDGES;
        int dl[EA_UNR];
        #pragma unroll
        for (int k = 0; k < EA_UNR; k++) {
            int e = e0 + t + k * 256;
            dl[k] = (e < e1) ? dst[e] : -1;     // all 13 loads independent, in flight
        }
        #pragma unroll
        for (int k = 0; k < EA_UNR; k++)
            if (dl[k] >= 0) atomicAdd(&hist[dl[k] >> 8], 1);
        __syncthreads();
        for (int i = t; i < BINS; i += 256)
            base_s[i] = (hist[i] > 0) ? atomicAdd(&bin_cur[i], hist[i]) : 0;
        __syncthreads();
        int sl[EA_UNR];
        #pragma unroll
        for (int k = 0; k < EA_UNR; k++) {
            int e = e0 + t + k * 256;
            sl[k] = (e < e1) ? src[e] : 0;
        }
        #pragma unroll
        for (int k = 0; k < EA_UNR; k++) {
            if (dl[k] >= 0) {
                int d = dl[k];
                int b = d >> 8;
                int r = atomicAdd(&rank[b], 1);
                int slot = base_s[b] + r;
                if (slot < BIN_CAP)
                    binned[(size_t)b * BIN_CAP + slot] = (unsigned int)(sl[k] | ((d & 255) << 16));
            }
        }
    } else if (blk < BA_BLOCKS + LB_BLOCKS) {
        // --- one-pass label bucketing into fixed per-label regions node_list[b*N ..] ---
        __shared__ int lcnt[8], lbase[8], lrank[8];
        int i = (blk - BA_BLOCKS) * 256 + t;
        if (t < 8) { lcnt[t] = 0; lrank[t] = 0; }
        __syncthreads();
        int b = -1;
        if (i < N_NODES) {
            int lab = label[i];
            b = (lab >= 1 && lab <= 7) ? (lab - 1) : 7;
            atomicAdd(&lcnt[b], 1);
        }
        __syncthreads();
        if (t < 8) lbase[t] = (lcnt[t] > 0) ? atomicAdd(&lab_cnt[t], lcnt[t]) : 0;
        __syncthreads();
        if (i < N_NODES) {
            int r = atomicAdd(&lrank[b], 1);
            node_list[(size_t)b * N_NODES + lbase[b] + r] = i;
        }
    } else {
        // --- W -> W^T bf16 ---
        int j = (blk - BA_BLOCKS - LB_BLOCKS) * 256 + t;
        if (j < 7 * DIM * DIM) {
            int b = j >> 14;
            int d = (j >> 7) & 127;
            int c = j & 127;
            Wt[((size_t)b * DIM + c) * DIM + d] = f2bf(W[j]);
        }
    }
}

// ---------------- Kernel 2: binB (counting sort) | LDS-staged MFMA transform ----------------
// Transform R6: 32-node tiles (2 MFMA sub-tiles/block) -> B-frags loaded once and
// reused, per-block fixed costs halved; lab_cnt preloaded with 8 PARALLEL loads
// (was 8 dependent L2 round trips); v_cvt_pk_bf16_f32 replaces 5-op f2bf.
__global__ __launch_bounds__(256) void phase2_kernel(
        const float* __restrict__ x, const float* __restrict__ att,
        const int* __restrict__ lab_cnt, const int* __restrict__ node_list,
        const unsigned short* __restrict__ Wt,
        const int* __restrict__ bin_cur, const unsigned int* __restrict__ binned,
        unsigned short* __restrict__ oxh, float* __restrict__ ai, float* __restrict__ aj,
        int* __restrict__ cnt, unsigned short* __restrict__ bucket) {
    __shared__ __align__(16) char smem[25600];   // union: binB 25600B | transform 17920B
    int t = threadIdx.x;
    int blk = blockIdx.x;

    if (blk < BINS) {
        // --- binB: sort one 256-node bin into padded LDS rows, bulk-write 24KB coalesced ---
        unsigned short (*rows)[DEG_CAP] = (unsigned short (*)[DEG_CAP])smem;  // 24576 B
        int* lcnt = (int*)(smem + 24576);                                     // 1024 B
        int b = blk;
        int m = bin_cur[b]; if (m > BIN_CAP) m = BIN_CAP;
        const unsigned int* bp = binned + (size_t)b * BIN_CAP;

        lcnt[t] = 0;
        __syncthreads();
        for (int i0 = 0; i0 < m; i0 += 1024) {
            unsigned int v[4];
            #pragma unroll
            for (int u = 0; u < 4; u++) {
                int i = i0 + u * 256 + t;
                v[u] = (i < m) ? bp[i] : 0u;    // 4 loads in flight
            }
            #pragma unroll
            for (int u = 0; u < 4; u++) {
                int i = i0 + u * 256 + t;
                if (i < m) {
                    int ln = (v[u] >> 16) & 255;
                    int p = atomicAdd(&lcnt[ln], 1);
                    if (p < DEG_CAP) rows[ln][p] = (unsigned short)(v[u] & 0xFFFF);
                }
            }
        }
        __syncthreads();
        int n = b * 256 + t;
        if (n < N_NODES) {
            int deg = lcnt[t];
            if (deg > DEG_CAP) deg = DEG_CAP;
            cnt[n] = deg;
        }
        // bulk coalesced write of the bin's whole bucket region (bucket padded to BINS*256 rows)
        uint4* gdst = (uint4*)(bucket + (size_t)b * 256 * DEG_CAP);
        const uint4* lsrc = (const uint4*)rows;
        #pragma unroll
        for (int k = 0; k < (256 * DEG_CAP * 2 / 16) / 256; k++)   // 6 iters
            gdst[t + k * 256] = lsrc[t + k * 256];
    } else {
        // --- MFMA transform: block per 32-node tile, wave per 32-col quarter ---
        int lc[8];
        #pragma unroll
        for (int q = 0; q < 8; q++) lc[q] = lab_cnt[q];   // 8 parallel loads

        int tile = blk - BINS;
        int b = 0, base = 0, tcnt = 0;
        #pragma unroll
        for (; b < 8; b++) {
            int c = lc[b];
            int nt = (c + 31) >> 5;
            if (tile < nt) { base = b * N_NODES + tile * 32; tcnt = c - tile * 32; break; }
            tile -= nt;
        }
        if (b == 8) return;            // block-uniform: safe before barriers
        if (tcnt > 32) tcnt = 32;

        float* xs  = (float*)smem;                           // [32][XS_STRIDE] = 16896 B
        float* red = (float*)(smem + 32 * XS_STRIDE * 4);    // [4][64] = 1024 B

        // stage 32 x-rows coalesced (512B each): 1024 float4 over 256 threads
        {
            const float4* x4 = (const float4*)x;
            int j = t;
            #pragma unroll
            for (int k = 0; k < 4; k++, j += 256) {
                int row = j >> 5;          // 0..31
                int c4  = j & 31;
                int node = node_list[base + ((row < tcnt) ? row : 0)];
                float4 v = x4[(size_t)node * 32 + c4];
                *(float4*)(xs + row * XS_STRIDE + c4 * 4) = v;
            }
        }
        __syncthreads();

        int wv = t >> 6;
        int lane = t & 63;
        int m = lane & 15;
        int quad = lane >> 4;

        floatx4 acc[2][2];
        #pragma unroll
        for (int st = 0; st < 2; st++)
            #pragma unroll
            for (int nl = 0; nl < 2; nl++)
                acc[st][nl] = (floatx4){0.f, 0.f, 0.f, 0.f};

        if (b < 7) {
            // B-fragments loaded ONCE, reused for both 16-row sub-tiles
            short8 bfrag[4][2];
            const unsigned short* WtB = Wt + (size_t)b * DIM * DIM;
            #pragma unroll
            for (int kk = 0; kk < 4; kk++)
                #pragma unroll
                for (int nl = 0; nl < 2; nl++) {
                    int c = wv * 32 + nl * 16 + m;
                    bfrag[kk][nl] = *(const short8*)(WtB + (size_t)c * DIM + kk * 32 + quad * 8);
                }
            #pragma unroll
            for (int st = 0; st < 2; st++) {
                #pragma unroll
                for (int kk = 0; kk < 4; kk++) {
                    const float* xp = xs + (st * 16 + m) * XS_STRIDE + kk * 32 + quad * 8;
                    union { short8 s8; unsigned int u[4]; } a;
                    a.u[0] = cvtpk_bf16(xp[0], xp[1]);
                    a.u[1] = cvtpk_bf16(xp[2], xp[3]);
                    a.u[2] = cvtpk_bf16(xp[4], xp[5]);
                    a.u[3] = cvtpk_bf16(xp[6], xp[7]);
                    #pragma unroll
                    for (int nl = 0; nl < 2; nl++)
                        acc[st][nl] = __builtin_amdgcn_mfma_f32_16x16x32_bf16(a.s8, bfrag[kk][nl], acc[st][nl], 0, 0, 0);
                }
            }
        }

        #pragma unroll
        for (int st = 0; st < 2; st++) {
            int nodes[4];
            #pragma unroll
            for (int r = 0; r < 4; r++) {
                int rw = st * 16 + quad * 4 + r;
                nodes[r] = node_list[base + ((rw < tcnt) ? rw : 0)];
            }
            float pi[4] = {0.f, 0.f, 0.f, 0.f};
            float pj[4] = {0.f, 0.f, 0.f, 0.f};
            #pragma unroll
            for (int nl = 0; nl < 2; nl++) {
                int c = wv * 32 + nl * 16 + m;
                float a1 = att[c];
                float a2 = att[DIM + c];
                #pragma unroll
                for (int r = 0; r < 4; r++) {
                    int rw = st * 16 + quad * 4 + r;
                    if (rw < tcnt) {
                        float xv = xs[rw * XS_STRIDE + c];       // fp32 residual from LDS
                        float v = (b < 7) ? (acc[st][nl][r] + xv) : xv;
                        oxh[(size_t)nodes[r] * DIM + c] = (unsigned short)(cvtpk_bf16(v, v) & 0xffff);
                        pi[r] += v * a1;
                        pj[r] += v * a2;
                    }
                }
            }
            #pragma unroll
            for (int r = 0; r < 4; r++) {
                #pragma unroll
                for (int off = 1; off < 16; off <<= 1) {
                    pi[r] += __shfl_xor(pi[r], off, 64);
                    pj[r] += __shfl_xor(pj[r], off, 64);
                }
            }
            if (m == 0) {
                #pragma unroll
                for (int r = 0; r < 4; r++) {
                    int node32 = st * 16 + quad * 4 + r;
                    red[wv * 64 + node32]      = pi[r];
                    red[wv * 64 + 32 + node32] = pj[r];
                }
            }
        }
        __syncthreads();
        if (t < 32 && t < tcnt) {
            int node = node_list[base + t];
            float si = 0.f, sj = 0.f;
            #pragma unroll
            for (int w2 = 0; w2 < 4; w2++) {
                si += red[w2 * 64 + t];
                sj += red[w2 * 64 + 32 + t];
            }
            ai[node] = si;
            aj[node] = sj;
        }
    }
}

// ---------------- Gather: wave per node; 4x16-lane groups, dwordx4 loads ----------------
// Frozen this round (R5 analysis: BW-bound at mixed L2/L3; ~205 MB mandatory).
__global__ __launch_bounds__(256) void gather8_kernel(
        const int* __restrict__ cnt, const unsigned short* __restrict__ bucket,
        const float* __restrict__ ai, const float* __restrict__ aj,
        const uint4* __restrict__ tab,     // oxh rows as 16 x uint4
        float* __restrict__ out) {
    __shared__ float wls[4][64];
    __shared__ int   sls[4][64];
    int wv = threadIdx.x >> 6;
    int lane = threadIdx.x & 63;
    int n = blockIdx.x * 4 + wv;
    int deg = cnt[n];
    if (deg > DEG_CAP) deg = DEG_CAP;
    const unsigned short* row = bucket + (size_t)n * DEG_CAP;
    float ain = ai[n];

    // phase A: lane i<deg = edge i; lane==deg = self loop; others weight 0
    float a = -INFINITY;
    int s = n;
    if (lane < deg) {
        s = row[lane];
        a = ain + aj[s];
        a = (a > 0.0f) ? a : 0.2f * a;
    } else if (lane == deg) {
        a = ain + aj[n];
        a = (a > 0.0f) ? a : 0.2f * a;
    }
    float mx = a;
    #pragma unroll
    for (int off = 32; off > 0; off >>= 1) mx = fmaxf(mx, __shfl_xor(mx, off, 64));
    float w = expf(a - mx);
    float ssum = w;
    #pragma unroll
    for (int off = 32; off > 0; off >>= 1) ssum += __shfl_xor(ssum, off, 64);
    float wn = w / (ssum + 1e-16f);

    wls[wv][lane] = wn;          // lanes > deg hold 0; lane == deg holds self weight
    sls[wv][lane] = s;
    __syncthreads();

    const float* wp = wls[wv];
    const int*   sp = sls[wv];
    float wsf = wp[deg];         // self-loop weight

    // phase B
    int g = lane >> 4;      // edge group 0..3
    int cl = lane & 15;     // col-block: cols [cl*8, cl*8+8)
    float ac0 = 0.f, ac1 = 0.f, ac2 = 0.f, ac3 = 0.f;
    float ac4 = 0.f, ac5 = 0.f, ac6 = 0.f, ac7 = 0.f;

    if (g == 0) {           // self row, counted once
        uint4 v = tab[(size_t)n * 16 + cl];
        ac0 += wsf * bf2f_lo(v.x); ac1 += wsf * bf2f_hi(v.x);
        ac2 += wsf * bf2f_lo(v.y); ac3 += wsf * bf2f_hi(v.y);
        ac4 += wsf * bf2f_lo(v.z); ac5 += wsf * bf2f_hi(v.z);
        ac6 += wsf * bf2f_lo(v.w); ac7 += wsf * bf2f_hi(v.w);
    }

    int niter = (deg + 3) >> 2;          // wave-uniform; max 12 (i max 47 < 64)
    int k = 0;
    for (; k + 4 <= niter; k += 4) {     // unroll 4: four rows in flight
        int i0 = g + 4 * k, i1 = i0 + 4, i2 = i0 + 8, i3 = i0 + 12;
        float w0 = wp[i0]; int s0 = sp[i0];
        float w1 = wp[i1]; int s1 = sp[i1];
        float w2 = wp[i2]; int s2 = sp[i2];
        float w3 = wp[i3]; int s3 = sp[i3];
        if (i0 >= deg) w0 = 0.0f;        // lane==deg slot is the SELF weight: mask it
        if (i1 >= deg) w1 = 0.0f;
        if (i2 >= deg) w2 = 0.0f;
        if (i3 >= deg) w3 = 0.0f;
        uint4 v0 = tab[(size_t)s0 * 16 + cl];
        uint4 v1 = tab[(size_t)s1 * 16 + cl];
        uint4 v2 = tab[(size_t)s2 * 16 + cl];
        uint4 v3 = tab[(size_t)s3 * 16 + cl];
        ac0 += w0 * bf2f_lo(v0.x); ac1 += w0 * bf2f_hi(v0.x);
        ac2 += w0 * bf2f_lo(v0.y); ac3 += w0 * bf2f_hi(v0.y);
        ac4 += w0 * bf2f_lo(v0.z); ac5 += w0 * bf2f_hi(v0.z);
        ac6 += w0 * bf2f_lo(v0.w); ac7 += w0 * bf2f_hi(v0.w);
        ac0 += w1 * bf2f_lo(v1.x); ac1 += w1 * bf2f_hi(v1.x);
        ac2 += w1 * bf2f_lo(v1.y); ac3 += w1 * bf2f_hi(v1.y);
        ac4 += w1 * bf2f_lo(v1.z); ac5 += w1 * bf2f_hi(v1.z);
        ac6 += w1 * bf2f_lo(v1.w); ac7 += w1 * bf2f_hi(v1.w);
        ac0 += w2 * bf2f_lo(v2.x); ac1 += w2 * bf2f_hi(v2.x);
        ac2 += w2 * bf2f_lo(v2.y); ac3 += w2 * bf2f_hi(v2.y);
        ac4 += w2 * bf2f_lo(v2.z); ac5 += w2 * bf2f_hi(v2.z);
        ac6 += w2 * bf2f_lo(v2.w); ac7 += w2 * bf2f_hi(v2.w);
        ac0 += w3 * bf2f_lo(v3.x); ac1 += w3 * bf2f_hi(v3.x);
        ac2 += w3 * bf2f_lo(v3.y); ac3 += w3 * bf2f_hi(v3.y);
        ac4 += w3 * bf2f_lo(v3.z); ac5 += w3 * bf2f_hi(v3.z);
        ac6 += w3 * bf2f_lo(v3.w); ac7 += w3 * bf2f_hi(v3.w);
    }
    for (; k < niter; k++) {
        int i0 = g + 4 * k;
        float w0 = (i0 < deg) ? wp[i0] : 0.0f;
        int s0 = sp[i0];
        uint4 v0 = tab[(size_t)s0 * 16 + cl];
        ac0 += w0 * bf2f_lo(v0.x); ac1 += w0 * bf2f_hi(v0.x);
        ac2 += w0 * bf2f_lo(v0.y); ac3 += w0 * bf2f_hi(v0.y);
        ac4 += w0 * bf2f_lo(v0.z); ac5 += w0 * bf2f_hi(v0.z);
        ac6 += w0 * bf2f_lo(v0.w); ac7 += w0 * bf2f_hi(v0.w);
    }

    // cross-group reduction (groups hold same cols at lane offsets 16/32/48)
    #pragma unroll
    for (int off = 16; off < 64; off <<= 1) {
        ac0 += __shfl_xor(ac0, off, 64); ac1 += __shfl_xor(ac1, off, 64);
        ac2 += __shfl_xor(ac2, off, 64); ac3 += __shfl_xor(ac3, off, 64);
        ac4 += __shfl_xor(ac4, off, 64); ac5 += __shfl_xor(ac5, off, 64);
        ac6 += __shfl_xor(ac6, off, 64); ac7 += __shfl_xor(ac7, off, 64);
    }
    if (g == 0) {
        float* op = out + (size_t)n * DIM + cl * 8;
        float4 o0; o0.x = ac0; o0.y = ac1; o0.z = ac2; o0.w = ac3;
        float4 o1; o1.x = ac4; o1.y = ac5; o1.z = ac6; o1.w = ac7;
        *(float4*)op = o0;
        *(float4*)(op + 4) = o1;
    }
}

extern "C" void kernel_launch(void* const* d_in, const int* in_sizes, int n_in,
                              void* d_out, int out_size, void* d_ws, size_t ws_size,
                              hipStream_t stream) {
    const float* x     = (const float*)d_in[0];
    const int*   ei    = (const int*)d_in[1];   // [2, E]
    const int*   label = (const int*)d_in[2];
    const float* W     = (const float*)d_in[3]; // [7, D, D]
    const float* att   = (const float*)d_in[4]; // [1, 1, 2D]
    float* out = (float*)d_out;

    const int* src = ei;
    const int* dst = ei + N_EDGES;

    // workspace (~27 MB). bucket padded to BINS*256 rows for binB's bulk write.
    char* w = (char*)d_ws;
    unsigned short* oxh    = (unsigned short*)w; w += sizeof(unsigned short) * (size_t)N_NODES * DIM;
    unsigned short* Wt     = (unsigned short*)w; w += sizeof(unsigned short) * 7 * DIM * DIM;
    unsigned short* bucket = (unsigned short*)w; w += sizeof(unsigned short) * (size_t)BINS * 256 * DEG_CAP;
    unsigned int*   binned = (unsigned int*)w;   w += sizeof(unsigned int) * (size_t)BINS * BIN_CAP;
    int*   cnt       = (int*)w;    w += sizeof(int) * N_NODES;
    int*   node_list = (int*)w;    w += sizeof(int) * (size_t)8 * N_NODES;
    float* ai        = (float*)w;  w += sizeof(float) * N_NODES;
    float* aj        = (float*)w;  w += sizeof(float) * N_NODES;
    // zero-region: lab_cnt(8) + bin_cur(BINS) contiguous, one tiny memset (816 B)
    int*   lab_cnt   = (int*)w;    w += sizeof(int) * 8;
    int*   bin_cur   = (int*)w;    w += sizeof(int) * BINS;

    hipMemsetAsync(lab_cnt, 0, sizeof(int) * (8 + BINS), stream);

    build_kernel<<<K1_GRID, 256, 0, stream>>>(src, dst, label, W,
                                              Wt, bin_cur, binned, lab_cnt, node_list);

    phase2_kernel<<<K2_GRID, 256, 0, stream>>>(x, att, lab_cnt, node_list, Wt,
                                               bin_cur, binned, oxh, ai, aj, cnt, bucket);

    gather8_kernel<<<(N_NODES + 3) / 4, 256, 0, stream>>>(cnt, bucket, ai, aj,
                                                          (const uint4*)oxh, out);
}